// Round 1
// baseline (70.420 us; speedup 1.0000x reference)
//
#include <hip/hip_runtime.h>

#define ALPHA 0.2f

__device__ __forceinline__ float leaky(float x){ return x > 0.f ? x : ALPHA * x; }
__device__ __forceinline__ float elu1 (float x){ return x > 0.f ? x : (__expf(x) - 1.f); }

// One block per (n, t'). 192 blocks, 256 threads.
// out = [ elu(h_prime) : 16*12*64*64 ][ attention : 16*12*64*64 ]  (f32)
__global__ __launch_bounds__(256) void gat_fused(
    const float* __restrict__ inp,   // [16,12,64,64]
    const float* __restrict__ W,     // [64,64]
    const float* __restrict__ av,    // [128]  (a[:,0])
    float* __restrict__ out)
{
    __shared__ __align__(16) float Ws[64*68];   // W, row stride 68 (16B-aligned rows)
    __shared__ float X [64*65];                 // own inp tile, pad 65
    __shared__ float H [64*65];                 // h = X @ W, pad 65
    __shared__ float aL[128];
    __shared__ float WaA[64], WaB[64], Wa1[64]; // W @ a[:64], W @ a[64:], sum
    __shared__ float sArr[2][64];               // per-tt row dots
    __shared__ float S0L[64], S1L[64];          // column sums of H halves (t'<6)
    __shared__ __align__(16) float attL[2][32]; // t'>=6 attention rows
    __shared__ __align__(16) float eluL[2][64]; // t'>=6 elu(h') rows

    const int bid = blockIdx.x;
    const int nI  = bid / 12;
    const int tP  = bid - nI * 12;
    const int tid = threadIdx.x;

    const bool firstHalf = (tP < 6);
    const int tt0 = firstHalf ? 2*tP : 2*tP - 12;
    const int tt1 = tt0 + 1;

    const size_t ownBase = (size_t)(nI*12 + tP) * 4096;

    // ---- global -> LDS (coalesced float4) ----
    const float4* W4 = (const float4*)W;
    const float4* X4 = (const float4*)(inp + ownBase);
    for (int i = tid; i < 1024; i += 256) {
        int r = i >> 4, c4 = (i & 15) << 2;
        float4 w = W4[i];
        float* dw = &Ws[r*68 + c4];
        dw[0]=w.x; dw[1]=w.y; dw[2]=w.z; dw[3]=w.w;
        float4 x = X4[i];
        float* dx = &X[r*65 + c4];
        dx[0]=x.x; dx[1]=x.y; dx[2]=x.z; dx[3]=x.w;
    }
    if (tid < 128) aL[tid] = av[tid];
    __syncthreads();

    // ---- Wa vectors (threads 0..63): Wa[c] = sum_k W[c][k]*a[k(+64)] ----
    if (tid < 64) {
        const int c = tid;
        const float* wr = &Ws[c*68];
        float sA = 0.f, sB = 0.f;
        #pragma unroll
        for (int k = 0; k < 64; ++k) { float w = wr[k]; sA += w*aL[k]; sB += w*aL[k+64]; }
        WaA[c] = sA; WaB[c] = sB; Wa1[c] = sA + sB;
    }

    // ---- h = X @ W : thread -> (v = tid>>2, k-chunk = (tid&3)*16) ----
    {
        const int v = tid >> 2, tk = tid & 3;
        float acc[16];
        #pragma unroll
        for (int j = 0; j < 16; ++j) acc[j] = 0.f;
        const float* xr = &X[v*65];
        for (int c = 0; c < 64; ++c) {
            const float xv = xr[c];
            const float4* wr4 = (const float4*)&Ws[c*68 + tk*16];
            float4 w0 = wr4[0], w1 = wr4[1], w2 = wr4[2], w3 = wr4[3];
            acc[ 0] += xv*w0.x; acc[ 1] += xv*w0.y; acc[ 2] += xv*w0.z; acc[ 3] += xv*w0.w;
            acc[ 4] += xv*w1.x; acc[ 5] += xv*w1.y; acc[ 6] += xv*w1.z; acc[ 7] += xv*w1.w;
            acc[ 8] += xv*w2.x; acc[ 9] += xv*w2.y; acc[10] += xv*w2.z; acc[11] += xv*w2.w;
            acc[12] += xv*w3.x; acc[13] += xv*w3.y; acc[14] += xv*w3.z; acc[15] += xv*w3.w;
        }
        float* hr = &H[v*65 + tk*16];
        #pragma unroll
        for (int j = 0; j < 16; ++j) hr[j] = acc[j];
    }
    __syncthreads();

    // ---- row dots against the two needed time-slices (global reads; L2/L3-resident) ----
    if (tid < 128) {
        const int q = tid >> 6, vv = tid & 63;
        const int ttq = q ? tt1 : tt0;
        const float4* xr = (const float4*)(inp + (size_t)(nI*12 + ttq)*4096 + vv*64);
        const float* wv = firstHalf ? Wa1 : ((vv & 1) ? WaB : WaA);
        float s = 0.f;
        #pragma unroll
        for (int u = 0; u < 16; ++u) {
            float4 x = xr[u];
            s += x.x*wv[4*u] + x.y*wv[4*u+1] + x.z*wv[4*u+2] + x.w*wv[4*u+3];
        }
        sArr[q][vv] = s;
    }
    __syncthreads();

    float* out1 = out + ownBase;            // elu(h_prime)
    float* out2 = out + 786432 + ownBase;   // attention

    if (firstHalf) {
        // column sums over the two halves of H rows
        if (tid < 64) {
            const int k = tid;
            float s0 = 0.f, s1 = 0.f;
            #pragma unroll
            for (int w = 0; w < 32; ++w) { s0 += H[w*65 + k]; s1 += H[(w+32)*65 + k]; }
            S0L[k] = s0; S1L[k] = s1;
        }
        __syncthreads();
        const int v = tid >> 2, tk = tid & 3;
        const int q = v >> 5, vp = v & 31;
        float A = leaky(sArr[q][2*vp]);
        float B = leaky(sArr[q][2*vp + 1]);
        float m  = fmaxf(A, B);
        float eA = __expf(A - m), eB = __expf(B - m);
        float inv = 1.f / (32.f * (eA + eB));
        float pA = eA * inv, pB = eB * inv;
        float4* o1 = (float4*)(out1 + v*64 + tk*16);
        #pragma unroll
        for (int u = 0; u < 4; ++u) {
            const int k0 = tk*16 + u*4;
            float4 r;
            r.x = elu1(pA*S0L[k0+0] + pB*S1L[k0+0]);
            r.y = elu1(pA*S0L[k0+1] + pB*S1L[k0+1]);
            r.z = elu1(pA*S0L[k0+2] + pB*S1L[k0+2]);
            r.w = elu1(pA*S0L[k0+3] + pB*S1L[k0+3]);
            o1[u] = r;
        }
        const float pv = (tk < 2) ? pA : pB;
        const float4 p4 = make_float4(pv, pv, pv, pv);
        float4* o2 = (float4*)(out2 + v*64 + tk*16);
        #pragma unroll
        for (int u = 0; u < 4; ++u) o2[u] = p4;
    } else {
        // 32-value softmax per q (rows repeat twice across w)
        if (tid < 64) {
            const int q = tid >> 5, wp = tid & 31;
            float cv = leaky(sArr[q][2*wp] + sArr[q][2*wp + 1]);
            float m = cv;
            #pragma unroll
            for (int mask = 16; mask; mask >>= 1) m = fmaxf(m, __shfl_xor(m, mask));
            float e = __expf(cv - m);
            float s = e;
            #pragma unroll
            for (int mask = 16; mask; mask >>= 1) s += __shfl_xor(s, mask);
            attL[q][wp] = e / (2.f * s);
        }
        __syncthreads();
        // h_prime rows (one per q), shared by 32 v's each
        if (tid < 128) {
            const int q = tid >> 6, k = tid & 63;
            float acc = 0.f;
            #pragma unroll
            for (int wp = 0; wp < 32; ++wp)
                acc += attL[q][wp] * (H[wp*65 + k] + H[(wp+32)*65 + k]);
            eluL[q][k] = elu1(acc);
        }
        __syncthreads();
        const int v = tid >> 2, tk = tid & 3;
        const int q = v >> 5;
        const float4* s1 = (const float4*)&eluL[q][tk*16];
        float4* o1 = (float4*)(out1 + v*64 + tk*16);
        #pragma unroll
        for (int u = 0; u < 4; ++u) o1[u] = s1[u];
        const float4* s2 = (const float4*)&attL[q][(tk & 1)*16];
        float4* o2 = (float4*)(out2 + v*64 + tk*16);
        #pragma unroll
        for (int u = 0; u < 4; ++u) o2[u] = s2[u];
    }
}

extern "C" void kernel_launch(void* const* d_in, const int* in_sizes, int n_in,
                              void* d_out, int out_size, void* d_ws, size_t ws_size,
                              hipStream_t stream) {
    const float* inp = (const float*)d_in[0];
    // d_in[1] = adj — dead code in the reference (both branches set attention = e)
    const float* W   = (const float*)d_in[2];
    const float* av  = (const float*)d_in[3];
    float* out = (float*)d_out;
    gat_fused<<<dim3(192), dim3(256), 0, stream>>>(inp, W, av, out);
}

// Round 2
// 66.818 us; speedup vs baseline: 1.0539x; 1.0539x over previous
//
#include <hip/hip_runtime.h>

#define ALPHA 0.2f

__device__ __forceinline__ float leaky(float x){ return x > 0.f ? x : ALPHA * x; }
__device__ __forceinline__ float elu1 (float x){ return x > 0.f ? x : (__expf(x) - 1.f); }

// One block per (n, t'). 192 blocks, 512 threads (8 waves -> 2 waves/SIMD).
// out = [ elu(h_prime) : 16*12*64*64 ][ attention : 16*12*64*64 ]  (f32)
__global__ __launch_bounds__(512) void gat_fused(
    const float* __restrict__ inp,   // [16,12,64,64]
    const float* __restrict__ W,     // [64,64]
    const float* __restrict__ av,    // [128]  (a[:,0])
    float* __restrict__ out)
{
    __shared__ __align__(16) float Ws[64*68];   // W, stride 68 (16B-aligned rows)
    __shared__ __align__(16) float X [64*68];   // own inp tile; reused as Hsum (t'>=6)
    __shared__ __align__(16) float H [64*68];   // h = X @ W
    __shared__ __align__(16) float aL[128];
    __shared__ __align__(16) float WaA[64], WaB[64], Wa1[64];
    __shared__ float sArr[2][64];               // per-tt row dots
    __shared__ float S0L[64], S1L[64];          // column sums of H halves (t'<6)
    __shared__ __align__(16) float attL[2][32]; // t'>=6 attention rows
    __shared__ __align__(16) float eluL[2][64]; // t'>=6 elu(h') rows

    const int bid = blockIdx.x;
    const int nI  = bid / 12;
    const int tP  = bid - nI * 12;
    const int tid = threadIdx.x;

    const bool firstHalf = (tP < 6);
    const int tt0 = firstHalf ? 2*tP : 2*tP - 12;
    const int tt1 = tt0 + 1;

    const size_t ownBase = (size_t)(nI*12 + tP) * 4096;

    // ---- issue cross-slice row prefetch FIRST (HBM-cold latency hides under GEMM) ----
    float4 rr[16];
    if (tid < 128) {
        const int q  = tid >> 6, vvl = tid & 63;
        const int ttq = q ? tt1 : tt0;
        const float4* xr = (const float4*)(inp + (size_t)(nI*12 + ttq)*4096 + vvl*64);
        #pragma unroll
        for (int u = 0; u < 16; ++u) rr[u] = xr[u];
    }

    // ---- global -> LDS staging (coalesced float4, 2 iters/thread) ----
    const float4* W4 = (const float4*)W;
    const float4* X4 = (const float4*)(inp + ownBase);
    #pragma unroll
    for (int i = tid; i < 1024; i += 512) {
        const int r = i >> 4, c4 = (i & 15) << 2;
        *(float4*)&Ws[r*68 + c4] = W4[i];
        *(float4*)&X [r*68 + c4] = X4[i];
    }
    if (tid < 128) aL[tid] = av[tid];
    __syncthreads();

    // ---- Wa vectors (wave 0) ----
    if (tid < 64) {
        const float4* wr4 = (const float4*)&Ws[tid*68];
        const float4* a4  = (const float4*)aL;
        float sA = 0.f, sB = 0.f;
        #pragma unroll
        for (int u = 0; u < 16; ++u) {
            const float4 w = wr4[u], x = a4[u], y = a4[u+16];
            sA += w.x*x.x + w.y*x.y + w.z*x.z + w.w*x.w;
            sB += w.x*y.x + w.y*y.y + w.z*y.z + w.w*y.w;
        }
        WaA[tid] = sA; WaB[tid] = sB; Wa1[tid] = sA + sB;
    }

    // ---- h = X @ W : v = tid>>3, 8 k-columns per thread, fully unrolled ----
    {
        const int v = tid >> 3, tk = tid & 7;
        float a0=0,a1=0,a2=0,a3=0,a4=0,a5=0,a6=0,a7=0;
        const float* xr = &X[v*68];
        #pragma unroll
        for (int c = 0; c < 64; ++c) {
            const float xv = xr[c];
            const float4* wr4 = (const float4*)&Ws[c*68 + tk*8];
            const float4 w0 = wr4[0], w1 = wr4[1];
            a0 += xv*w0.x; a1 += xv*w0.y; a2 += xv*w0.z; a3 += xv*w0.w;
            a4 += xv*w1.x; a5 += xv*w1.y; a6 += xv*w1.z; a7 += xv*w1.w;
        }
        float* hr = &H[v*68 + tk*8];
        *(float4*)hr       = make_float4(a0,a1,a2,a3);
        *(float4*)(hr + 4) = make_float4(a4,a5,a6,a7);
    }
    __syncthreads();

    // ---- dots from prefetched regs (waves 0-1) ∥ column sums / Hsum (waves 2+) ----
    if (tid < 128) {
        const int q = tid >> 6, vvl = tid & 63;
        const float* wv = firstHalf ? Wa1 : ((vvl & 1) ? WaB : WaA);
        const float4* wv4 = (const float4*)wv;
        float s = 0.f;
        #pragma unroll
        for (int u = 0; u < 16; ++u) {
            const float4 x = rr[u], w = wv4[u];
            s += x.x*w.x + x.y*w.y + x.z*w.z + x.w*w.w;
        }
        sArr[q][vvl] = s;
    } else if (firstHalf) {
        if (tid < 192) {            // wave 2: column sums of H halves
            const int k = tid - 128;
            float s0 = 0.f, s1 = 0.f;
            #pragma unroll
            for (int w = 0; w < 32; ++w) { s0 += H[w*68 + k]; s1 += H[(w+32)*68 + k]; }
            S0L[k] = s0; S1L[k] = s1;
        }
    } else {
        if (tid < 384) {            // waves 2-5: Hsum[wp][k] = H[wp]+H[wp+32] into X
            const int idx = tid - 128;          // 0..255, 8 floats each
            const int wp = idx >> 5, k0 = (idx & 31) << 1;
            // 256 threads * 8 = 2048 elems: wp=idx>>3? -> use float4 pairs
        }
        if (tid < 384) {
            const int idx = tid - 128;
            const int wp = idx >> 3, k0 = (idx & 7) * 8;
            const float4* h0 = (const float4*)&H[wp*68 + k0];
            const float4* h1 = (const float4*)&H[(wp+32)*68 + k0];
            float4 u0 = h0[0], u1 = h0[1], v0 = h1[0], v1 = h1[1];
            float4 r0 = make_float4(u0.x+v0.x, u0.y+v0.y, u0.z+v0.z, u0.w+v0.w);
            float4 r1 = make_float4(u1.x+v1.x, u1.y+v1.y, u1.z+v1.z, u1.w+v1.w);
            *(float4*)&X[wp*68 + k0]     = r0;
            *(float4*)&X[wp*68 + k0 + 4] = r1;
        }
    }
    __syncthreads();

    float* out1 = out + ownBase;            // elu(h_prime)
    float* out2 = out + 786432 + ownBase;   // attention

    if (firstHalf) {
        const int v = tid >> 3, tk = tid & 7;
        const int q = v >> 5, vp = v & 31;
        const float A = leaky(sArr[q][2*vp]);
        const float B = leaky(sArr[q][2*vp + 1]);
        const float m  = fmaxf(A, B);
        const float eA = __expf(A - m), eB = __expf(B - m);
        const float inv = 1.f / (32.f * (eA + eB));
        const float pA = eA * inv, pB = eB * inv;
        const int k0 = tk * 8;
        float4 r0, r1;
        r0.x = elu1(pA*S0L[k0+0] + pB*S1L[k0+0]);
        r0.y = elu1(pA*S0L[k0+1] + pB*S1L[k0+1]);
        r0.z = elu1(pA*S0L[k0+2] + pB*S1L[k0+2]);
        r0.w = elu1(pA*S0L[k0+3] + pB*S1L[k0+3]);
        r1.x = elu1(pA*S0L[k0+4] + pB*S1L[k0+4]);
        r1.y = elu1(pA*S0L[k0+5] + pB*S1L[k0+5]);
        r1.z = elu1(pA*S0L[k0+6] + pB*S1L[k0+6]);
        r1.w = elu1(pA*S0L[k0+7] + pB*S1L[k0+7]);
        float4* o1 = (float4*)(out1 + v*64 + k0);
        o1[0] = r0; o1[1] = r1;
        const float pv = (tk < 4) ? pA : pB;
        const float4 p4 = make_float4(pv, pv, pv, pv);
        float4* o2 = (float4*)(out2 + v*64 + k0);
        o2[0] = p4; o2[1] = p4;
    } else {
        // 32-value softmax per q (rows repeat twice across w)
        if (tid < 64) {
            const int q = tid >> 5, wp = tid & 31;
            float cv = leaky(sArr[q][2*wp] + sArr[q][2*wp + 1]);
            float m = cv;
            #pragma unroll
            for (int mask = 16; mask; mask >>= 1) m = fmaxf(m, __shfl_xor(m, mask));
            const float e = __expf(cv - m);
            float s = e;
            #pragma unroll
            for (int mask = 16; mask; mask >>= 1) s += __shfl_xor(s, mask);
            attL[q][wp] = e / (2.f * s);
        }
        __syncthreads();
        // h_prime rows (one per q) from Hsum (in X)
        if (tid < 128) {
            const int q = tid >> 6, k = tid & 63;
            float acc = 0.f;
            #pragma unroll
            for (int wp = 0; wp < 32; ++wp)
                acc += attL[q][wp] * X[wp*68 + k];
            eluL[q][k] = elu1(acc);
        }
        __syncthreads();
        const int v = tid >> 3, tk = tid & 7;
        const int q = v >> 5;
        const int k0 = tk * 8;
        const float4* s1 = (const float4*)&eluL[q][k0];
        float4* o1 = (float4*)(out1 + v*64 + k0);
        o1[0] = s1[0]; o1[1] = s1[1];
        const float4* s2 = (const float4*)&attL[q][(tk & 3)*8];
        float4* o2 = (float4*)(out2 + v*64 + k0);
        o2[0] = s2[0]; o2[1] = s2[1];
    }
}

extern "C" void kernel_launch(void* const* d_in, const int* in_sizes, int n_in,
                              void* d_out, int out_size, void* d_ws, size_t ws_size,
                              hipStream_t stream) {
    const float* inp = (const float*)d_in[0];
    // d_in[1] = adj — dead code in the reference (both branches set attention = e)
    const float* W   = (const float*)d_in[2];
    const float* av  = (const float*)d_in[3];
    float* out = (float*)d_out;
    gat_fused<<<dim3(192), dim3(512), 0, stream>>>(inp, W, av, out);
}